// Round 18
// baseline (36.616 us; speedup 1.0000x reference)
//
#include <hip/hip_runtime.h>
#include <hip/hip_bf16.h>

using u32 = unsigned int;
using u16 = unsigned short;

typedef __attribute__((ext_vector_type(8))) _Float16 half8;
typedef __attribute__((ext_vector_type(2))) _Float16 half2v;
typedef __attribute__((ext_vector_type(16))) float f32x16;
typedef __attribute__((ext_vector_type(4))) u32 u32x4;

#define IN_K   4096
#define OUT_N  14336
#define NST    16                // 16 stages x 64k = 1024k per k-quarter wave

// ---------------------------------------------------------------------------
// prep: x f32[64][4096] -> xs f16 in MFMA-fragment order.
__global__ __launch_bounds__(256) void prep_kernel(const float* __restrict__ x,
                                                   u16* __restrict__ xs) {
  const int t = blockIdx.x * 256 + threadIdx.x;   // 32768 threads
  const int c = t >> 6;        // chunk 0..511
  const int r = t & 63;        // row
  const float* px = x + r * IN_K + c * 8;
  const float4 a = *(const float4*)px;
  const float4 b = *(const float4*)(px + 4);
  const float af[4] = {a.x, a.y, a.z, a.w};
  const float bf[4] = {b.x, b.y, b.z, b.w};
  union { u32x4 v; u32 u[4]; } o;
#pragma unroll
  for (int i = 0; i < 4; ++i) {
    const _Float16 hl = (_Float16)af[i];   // k = 8c + i
    const _Float16 hh = (_Float16)bf[i];   // k = 8c + i + 4
    u16 lo, hi;
    __builtin_memcpy(&lo, &hl, 2);
    __builtin_memcpy(&hi, &hh, 2);
    o.u[i] = (u32)lo | ((u32)hi << 16);
  }
  *(u32x4*)(xs + (size_t)t * 8) = o.v;
}

// ---------------------------------------------------------------------------
// repack: qw [512][14336] row-major -> qwt [448 cb][512 row][32 col]
// (64 KB contiguous per col-block = exact qgemm consumption order).
// LDS-tiled transpose, both sides coalesced: reads 256-B wave segments,
// writes 4-KB contiguous runs per col-block. Grid 896 x 256.
__global__ __launch_bounds__(256) void repack_kernel(const u32* __restrict__ qw,
                                                     u32* __restrict__ qwt) {
  __shared__ u32 lds[32][257];               // +1 pad: conflict-free/2-way
  const int wg = blockIdx.x;                 // 16 row-tiles x 56 col-tiles
  const int rt = wg / 56, ct = wg % 56;
  const int row0 = rt * 32;
  const int col0 = ct * 256;
  const int t = threadIdx.x;
#pragma unroll
  for (int r = 0; r < 32; ++r)               // 256-B segments per wave
    lds[r][t] = qw[(size_t)(row0 + r) * OUT_N + col0 + t];
  __syncthreads();
  const int row = t >> 3, cg = t & 7;
#pragma unroll
  for (int cb = 0; cb < 8; ++cb) {           // 8 col-blocks of 32 cols
    const u32 a0 = lds[row][cb * 32 + cg * 4 + 0];
    const u32 a1 = lds[row][cb * 32 + cg * 4 + 1];
    const u32 a2 = lds[row][cb * 32 + cg * 4 + 2];
    const u32 a3 = lds[row][cb * 32 + cg * 4 + 3];
    u32x4 v = {a0, a1, a2, a3};
    // 256 threads -> 4 KB contiguous run per cb
    *(u32x4*)(qwt + ((size_t)(ct * 8 + cb) * 512 + row0 + row) * 32 + cg * 4) = v;
  }
}

// dequant one qweight word (8 weights, fragment order) -> f16x8 B-fragment
static __device__ __forceinline__ half8 dequant8(u32 q, half2v hz, half2v s2) {
  const u32 p0 = (q & 0x000F000Fu) | 0x64006400u;          // (n0,n4)+1024
  const u32 p1 = ((q >> 4) & 0x000F000Fu) | 0x64006400u;   // (n1,n5)+1024
  const u32 p2 = ((q >> 8) & 0x000F000Fu) | 0x64006400u;   // (n2,n6)+1024
  const u32 p3 = ((q >> 12) & 0x000F000Fu) | 0x64006400u;  // (n3,n7)+1024
  half2v t0, t1, t2, t3;
  __builtin_memcpy(&t0, &p0, 4);
  __builtin_memcpy(&t1, &p1, 4);
  __builtin_memcpy(&t2, &p2, 4);
  __builtin_memcpy(&t3, &p3, 4);
  union { half8 v; half2v h[4]; } bb;
  bb.h[0] = (t0 - hz) * s2;    // exact int sub, then scale (v_pk_*_f16)
  bb.h[1] = (t1 - hz) * s2;
  bb.h[2] = (t2 - hz) * s2;
  bb.h[3] = (t3 - hz) * s2;
  return bb.v;
}

// ---------------------------------------------------------------------------
// Fused qgemm: grid 448 x 256 thr, 4 private k-quarter waves, barrier-free
// K loop (R14 structure). SEQQ: Q stream reads the repacked qwt -- each wave's
// 16 KB is fully contiguous, one w16 global_load_lds per 64k stage (sequential
// 1-KB coalesced). Fallback (!SEQQ): original strided qw reads.
template <bool SEQQ>
__global__ __launch_bounds__(256, 2) void qgemm_kernel(
    const u32* __restrict__ qwsrc, const u32* __restrict__ qz,
    const float* __restrict__ scal, const u16* __restrict__ xs,
    const float* __restrict__ bias, float* __restrict__ out) {
  __shared__ alignas(16) char smem[73728];   // 4 waves x 18 KB
  const int tid = threadIdx.x;               // 0..255
  const int lane = tid & 63;
  const int g = lane >> 5;                   // k-half within 16k MFMA step
  const int nn = lane & 31;                  // col within 32-col tile
  const int kq = tid >> 6;                   // wave = k-quarter 0..3
  const int bx = blockIdx.x;
  const int bxp = (bx & 7) * 56 + (bx >> 3); // XCD-contiguous col-block
  const int colabs = bxp * 32 + nn;
  const int zsh = (nn & 7) * 4;
  char* const base = smem + kq * 18432;      // private: A 2x8KB @0, Q 2x1KB @16384

  f32x16 acc0, acc1;
#pragma unroll
  for (int i = 0; i < 16; ++i) { acc0[i] = 0.f; acc1[i] = 0.f; }

  // scales & zero-words for this quarter's 8 groups -> registers, then drain
  float sv[8]; u32 zv[8];
#pragma unroll
  for (int t = 0; t < 8; ++t) {
    sv[t] = scal[(size_t)(kq * 8 + t) * OUT_N + colabs];
    zv[t] = qz[(size_t)(kq * 8 + t) * (OUT_N / 8) + (colabs >> 3)];
  }
  asm volatile("s_waitcnt vmcnt(0)" ::: "memory");

  // wave's sequential Q base (SEQQ): 16 KB contiguous
  const u32* qseq = qwsrc + ((size_t)bxp * 512 + kq * 128) * 32;

  // per-wave stage issue: A 8 instr + Q 1 instr = 9 VMEM
  auto issue = [&](int st) {
    const int slot = st & 1;
    char* ab = base + slot * 8192;
    char* qb = base + 16384 + slot * 1024;
    const u16* asrc = xs + (size_t)(kq * 128 + st * 8) * 512;   // 8 KB linear
#pragma unroll
    for (int r = 0; r < 8; ++r) {
      const int p = r * 64 + lane;           // 16B chunk 0..511
      __builtin_amdgcn_global_load_lds(
          (const __attribute__((address_space(1))) void*)(asrc + p * 8),
          (__attribute__((address_space(3))) void*)(ab + p * 16), 16, 0, 0);
    }
    if (SEQQ) {
      // one contiguous 1-KB stage: lane l takes bytes l*16..+16
      __builtin_amdgcn_global_load_lds(
          (const __attribute__((address_space(1))) void*)(qseq + st * 256 + lane * 4),
          (__attribute__((address_space(3))) void*)(qb + lane * 16), 16, 0, 0);
    } else {
      const int j = lane >> 3, cg = lane & 7;  // 8 rows x 128 B (strided)
      const u32* src = qwsrc + (size_t)(kq * 128 + st * 8 + j) * OUT_N
                             + bxp * 32 + cg * 4;
      __builtin_amdgcn_global_load_lds(
          (const __attribute__((address_space(1))) void*)src,
          (__attribute__((address_space(3))) void*)(qb + lane * 16), 16, 0, 0);
    }
  };

  issue(0); issue(1);                        // 18 outstanding (per wave)

#pragma unroll
  for (int st = 0; st < NST; ++st) {
    if (st < NST - 1)
      asm volatile("s_waitcnt vmcnt(9)" ::: "memory");  // own stage st done
    else
      asm volatile("s_waitcnt vmcnt(0)" ::: "memory");

    const int gi = st >> 1;                  // group = 128 k = 2 stages
    const u32 zq = (zv[gi] >> zsh) & 0xFu;
    const u32 hzu = 0x64016401u + zq * 0x00010001u;     // f16x2 of (1025+z)
    half2v hz; __builtin_memcpy(&hz, &hzu, 4);
    const _Float16 hs = (_Float16)sv[gi];
    const half2v s2 = {hs, hs};

    const u16* ab = (const u16*)(base + (st & 1) * 8192);
    const u32* qb = (const u32*)(base + 16384 + (st & 1) * 1024);
    __builtin_amdgcn_s_setprio(1);
#pragma unroll
    for (int s = 0; s < 4; ++s) {
      const int cl = s * 2 + g;              // qw row within stage (0..7)
      const half8 a0 = *(const half8*)(ab + (cl * 64 + nn) * 8);
      const half8 a1 = *(const half8*)(ab + (cl * 64 + nn + 32) * 8);
      const u32 q = qb[cl * 32 + nn];        // [8 rows][32 cols] layout
      const half8 bb = dequant8(q, hz, s2);
      acc0 = __builtin_amdgcn_mfma_f32_32x32x16_f16(a0, bb, acc0, 0, 0, 0);
      acc1 = __builtin_amdgcn_mfma_f32_32x32x16_f16(a1, bb, acc1, 0, 0, 0);
    }
    __builtin_amdgcn_s_setprio(0);

    if (st + 2 < NST) {
      asm volatile("s_waitcnt lgkmcnt(0)" ::: "memory"); // WAR on own slot
      issue(st + 2);
    }
  }

  // ---- in-block split-K reduction via LDS (reuses ring space) ----
  __syncthreads();                           // all waves done computing
  float* ep = (float*)smem + kq * 2048;      // [64 rows][32 cols] f32 = 8 KB
#pragma unroll
  for (int r = 0; r < 16; ++r) {
    const int row0 = (r & 3) + 8 * (r >> 2) + 4 * g;
    ep[row0 * 32 + nn] = acc0[r];
    ep[(row0 + 32) * 32 + nn] = acc1[r];
  }
  __syncthreads();
  // 256 threads x 8 f32: sum 4 quarters + bias -> out (order: bias, q0..q3)
  const int pos = tid * 8;                   // 0..2040
  const int row = pos >> 5;
  const int colb = pos & 31;
  const float* eb = (const float*)smem;
  float4 v0 = *(const float4*)(bias + bxp * 32 + colb);
  float4 v1 = *(const float4*)(bias + bxp * 32 + colb + 4);
#pragma unroll
  for (int q = 0; q < 4; ++q) {
    const float4 a = *(const float4*)(eb + q * 2048 + pos);
    const float4 b = *(const float4*)(eb + q * 2048 + pos + 4);
    v0.x += a.x; v0.y += a.y; v0.z += a.z; v0.w += a.w;
    v1.x += b.x; v1.y += b.y; v1.z += b.z; v1.w += b.w;
  }
  float* po = out + (size_t)row * OUT_N + bxp * 32 + colb;
  *(float4*)po = v0;
  *(float4*)(po + 4) = v1;
}

// ---------------------------------------------------------------------------
extern "C" void kernel_launch(void* const* d_in, const int* in_sizes, int n_in,
                              void* d_out, int out_size, void* d_ws, size_t ws_size,
                              hipStream_t stream) {
  (void)in_sizes; (void)n_in; (void)out_size;
  const float* x    = (const float*)d_in[0];
  const u32*   qw   = (const u32*)d_in[1];
  const u32*   qz   = (const u32*)d_in[2];
  const float* sc   = (const float*)d_in[3];
  const float* bias = (const float*)d_in[4];
  // d_in[5] = g_idx: sequential k/128 for this problem; folded into indexing.
  float* out = (float*)d_out;

  const size_t XS_BYTES  = (size_t)64 * IN_K * 2;              // 512 KB
  const size_t QWT_BYTES = (size_t)448 * 512 * 32 * 4;         // 29.36 MB
  u16* xs = (u16*)d_ws;

  prep_kernel<<<128, 256, 0, stream>>>(x, xs);

  if (ws_size >= XS_BYTES + QWT_BYTES) {
    u32* qwt = (u32*)((char*)d_ws + XS_BYTES);
    repack_kernel<<<896, 256, 0, stream>>>(qw, qwt);
    qgemm_kernel<true><<<448, 256, 0, stream>>>(qwt, qz, sc, xs, bias, out);
  } else {
    qgemm_kernel<false><<<448, 256, 0, stream>>>(qw, qz, sc, xs, bias, out);
  }
}

// Round 19
// 29.229 us; speedup vs baseline: 1.2527x; 1.2527x over previous
//
#include <hip/hip_runtime.h>
#include <hip/hip_bf16.h>

using u32 = unsigned int;
using u16 = unsigned short;

typedef __attribute__((ext_vector_type(8))) _Float16 half8;
typedef __attribute__((ext_vector_type(2))) _Float16 half2v;
typedef __attribute__((ext_vector_type(16))) float f32x16;
typedef __attribute__((ext_vector_type(4))) u32 u32x4;

#define IN_K   4096
#define OUT_N  14336
#define NST    16                // 16 stages x 64k = 1024k per k-quarter

// ---------------------------------------------------------------------------
// prep: x f32[64][4096] -> xs f16 in MFMA-fragment order.
// xs layout: [512 chunks][64 rows][8 f16]; chunk c covers k = 8c + perm[j],
// perm = {0,4,1,5,2,6,3,7} (matches pair-dequant element order).
__global__ __launch_bounds__(256) void prep_kernel(const float* __restrict__ x,
                                                   u16* __restrict__ xs) {
  const int t = blockIdx.x * 256 + threadIdx.x;   // 32768 threads
  const int c = t >> 6;        // chunk 0..511
  const int r = t & 63;        // row
  const float* px = x + r * IN_K + c * 8;
  const float4 a = *(const float4*)px;
  const float4 b = *(const float4*)(px + 4);
  const float af[4] = {a.x, a.y, a.z, a.w};
  const float bf[4] = {b.x, b.y, b.z, b.w};
  union { u32x4 v; u32 u[4]; } o;
#pragma unroll
  for (int i = 0; i < 4; ++i) {
    const _Float16 hl = (_Float16)af[i];   // k = 8c + i
    const _Float16 hh = (_Float16)bf[i];   // k = 8c + i + 4
    u16 lo, hi;
    __builtin_memcpy(&lo, &hl, 2);
    __builtin_memcpy(&hi, &hh, 2);
    o.u[i] = (u32)lo | ((u32)hi << 16);
  }
  *(u32x4*)(xs + (size_t)t * 8) = o.v;
}

// dequant one qweight word (8 weights, fragment order) -> f16x8 B-fragment
static __device__ __forceinline__ half8 dequant8(u32 q, half2v hz, half2v s2) {
  const u32 p0 = (q & 0x000F000Fu) | 0x64006400u;          // (n0,n4)+1024
  const u32 p1 = ((q >> 4) & 0x000F000Fu) | 0x64006400u;   // (n1,n5)+1024
  const u32 p2 = ((q >> 8) & 0x000F000Fu) | 0x64006400u;   // (n2,n6)+1024
  const u32 p3 = ((q >> 12) & 0x000F000Fu) | 0x64006400u;  // (n3,n7)+1024
  half2v t0, t1, t2, t3;
  __builtin_memcpy(&t0, &p0, 4);
  __builtin_memcpy(&t1, &p1, 4);
  __builtin_memcpy(&t2, &p2, 4);
  __builtin_memcpy(&t3, &p3, 4);
  union { half8 v; half2v h[4]; } bb;
  bb.h[0] = (t0 - hz) * s2;    // exact int sub, then scale (v_pk_*_f16)
  bb.h[1] = (t1 - hz) * s2;
  bb.h[2] = (t2 - hz) * s2;
  bb.h[3] = (t3 - hz) * s2;
  return bb.v;
}

// ---------------------------------------------------------------------------
__global__ __launch_bounds__(256) void bias_init_kernel(const float* __restrict__ bias,
                                                        float* __restrict__ out) {
  const int i = (blockIdx.x * 256 + threadIdx.x) * 4;
  const int col = i % OUT_N;
  *(float4*)(out + i) = *(const float4*)(bias + col);
}

// reduce: out = bias + part[bx][0] + part[bx][1]; part tiled [bx][by][64][128]
__global__ __launch_bounds__(256) void reduce_kernel(const float* __restrict__ part,
                                                     const float* __restrict__ bias,
                                                     float* __restrict__ out) {
  const int bx = blockIdx.x, ry = blockIdx.y, t = threadIdx.x;
  const int row = ry * 8 + (t >> 5);
  const int c4 = (t & 31) * 4;
  const float4 p0 = *(const float4*)(part + ((size_t)bx * 2 + 0) * 8192 + row * 128 + c4);
  const float4 p1 = *(const float4*)(part + ((size_t)bx * 2 + 1) * 8192 + row * 128 + c4);
  const float4 bv = *(const float4*)(bias + bx * 128 + c4);
  float4 r;
  r.x = bv.x + p0.x + p1.x;
  r.y = bv.y + p0.y + p1.y;
  r.z = bv.z + p0.z + p1.z;
  r.w = bv.w + p0.w + p1.w;
  *(float4*)(out + (size_t)row * OUT_N + bx * 128 + c4) = r;
}

// ---------------------------------------------------------------------------
// qgemm: grid (112, 2), 512 thr (8 waves). Block = 128 cols x 2048 k.
// 8 waves = 2 k-quarters x 4 col-slices; each quarter's 4 waves SHARE its
// staged stages (A 8 KB + Q 4 KB per 64-k stage, ring-2, 3 gl_lds per thread,
// exact vmcnt(3)) -> chip staged bytes: A 57 MB + Q 29 MB (R13-18 staged
// 144-258 MB; model: gl_lds path ~6.5 TB/s is the binding ceiling).
// Quarters reduced in-block via LDS; splitk=2 partials across blockIdx.y.
template <bool ATOMIC>
__global__ __launch_bounds__(512, 4) void qgemm_kernel(
    const u32* __restrict__ qw, const u32* __restrict__ qz,
    const float* __restrict__ scal, const u16* __restrict__ xs,
    float* __restrict__ dst) {
  __shared__ alignas(16) char smem[65536];   // staging 48 KB; epilogue 64 KB
  const int tid = threadIdx.x;               // 0..511
  const int lane = tid & 63;
  const int g = lane >> 5;                   // k-half within 16k MFMA step
  const int nn = lane & 31;
  const int wv = tid >> 6;                   // 0..7
  const int kq2 = wv >> 2;                   // k-quarter 0/1
  const int cs = wv & 3;                     // col-slice (32 cols)
  const int qt = tid & 255;                  // thread id within quarter group
  const int bx = blockIdx.x;
  const int by = blockIdx.y;
  const int colabs = bx * 128 + cs * 32 + nn;
  const int kbase = (by * 2 + kq2) * 1024;   // this quarter's k origin
  const int rowb = kbase >> 3;               // qw row base == xs chunk base
  const int grp0 = kbase >> 7;               // first of 8 quant groups
  const int zsh = (nn & 7) * 4;
  char* const region = smem + kq2 * 24576;   // A 2x8KB @0, Q 2x4KB @16384

  f32x16 acc0, acc1;
#pragma unroll
  for (int i = 0; i < 16; ++i) { acc0[i] = 0.f; acc1[i] = 0.f; }

  // scales & zero-words for this quarter's 8 groups -> registers, then drain
  // so the counted vmcnt region contains ONLY staging loads.
  float sv[8]; u32 zv[8];
#pragma unroll
  for (int t = 0; t < 8; ++t) {
    sv[t] = scal[(size_t)(grp0 + t) * OUT_N + colabs];
    zv[t] = qz[(size_t)(grp0 + t) * (OUT_N / 8) + (colabs >> 3)];
  }
  asm volatile("s_waitcnt vmcnt(0)" ::: "memory");

  // stage issue (shared by the quarter's 4 waves): 3 gl_lds per thread
  auto issue = [&](int st) {
    char* ab = region + (st & 1) * 8192;
    char* qb = region + 16384 + (st & 1) * 4096;
    const u16* asrc = xs + (size_t)(rowb + st * 8) * 512;   // 8 KB linear
#pragma unroll
    for (int r = 0; r < 2; ++r) {
      const int p = r * 256 + qt;            // 16B chunk 0..511
      __builtin_amdgcn_global_load_lds(
          (const __attribute__((address_space(1))) void*)(asrc + p * 8),
          (__attribute__((address_space(3))) void*)(ab + p * 16), 16, 0, 0);
    }
    const int j = qt >> 5, cg = qt & 31;     // Q: 8 rows x 512 B
    const u32* qsrc = qw + (size_t)(rowb + st * 8 + j) * OUT_N + bx * 128 + cg * 4;
    __builtin_amdgcn_global_load_lds(
        (const __attribute__((address_space(1))) void*)qsrc,
        (__attribute__((address_space(3))) void*)(qb + qt * 16), 16, 0, 0);
  };

  issue(0);                                  // 3 outstanding

#pragma unroll
  for (int st = 0; st < NST; ++st) {
    if (st == 0) {
      issue(1);                                          // 6 outstanding
      asm volatile("s_waitcnt vmcnt(3)" ::: "memory");   // stage 0 done
    } else if (st < NST - 1) {
      __builtin_amdgcn_s_barrier();                      // WAR: slot free
      issue(st + 1);
      asm volatile("s_waitcnt vmcnt(3)" ::: "memory");   // stage st done
    } else {
      __builtin_amdgcn_s_barrier();
      asm volatile("s_waitcnt vmcnt(0)" ::: "memory");
    }
    __builtin_amdgcn_s_barrier();                        // stage st visible
    asm volatile("" ::: "memory");

    const int gi = st >> 1;                  // group = 128 k = 2 stages
    const u32 zq = (zv[gi] >> zsh) & 0xFu;
    const u32 hzu = 0x64016401u + zq * 0x00010001u;      // f16x2 of (1025+z)
    half2v hz; __builtin_memcpy(&hz, &hzu, 4);
    const _Float16 hs = (_Float16)sv[gi];
    const half2v s2 = {hs, hs};

    const char* ab = region + (st & 1) * 8192;
    const char* qb = region + 16384 + (st & 1) * 4096;
    __builtin_amdgcn_s_setprio(1);
#pragma unroll
    for (int s = 0; s < 4; ++s) {
      const int cl = s * 2 + g;              // 8k-chunk within stage (0..7)
      const half8 a0 = *(const half8*)(ab + (cl * 64 + nn) * 16);
      const half8 a1 = *(const half8*)(ab + (cl * 64 + nn + 32) * 16);
      const u32 q = *(const u32*)(qb + (cl * 128 + cs * 32 + nn) * 4);
      const half8 bb = dequant8(q, hz, s2);
      acc0 = __builtin_amdgcn_mfma_f32_32x32x16_f16(a0, bb, acc0, 0, 0, 0);
      acc1 = __builtin_amdgcn_mfma_f32_32x32x16_f16(a1, bb, acc1, 0, 0, 0);
    }
    __builtin_amdgcn_s_setprio(0);
  }

  // ---- in-block quarter reduction via LDS (reuses staging space) ----
  __syncthreads();                           // all staging reads done
  float* ep = (float*)smem + kq2 * 8192;     // [64 rows][128 cols] f32 = 32 KB
#pragma unroll
  for (int r = 0; r < 16; ++r) {
    const int row0 = (r & 3) + 8 * (r >> 2) + 4 * g;
    ep[row0 * 128 + cs * 32 + nn] = acc0[r];
    ep[(row0 + 32) * 128 + cs * 32 + nn] = acc1[r];
  }
  __syncthreads();
  // 512 thr x 16 f32: partial = q0 + q1 (deterministic order)
  const float* e0 = (const float*)smem;
  const float* e1 = e0 + 8192;
  if (ATOMIC) {
#pragma unroll
    for (int i = 0; i < 4; ++i) {
      const int pos = tid * 16 + i * 4;
      const int row = pos >> 7, col = pos & 127;
      const float4 a = *(const float4*)(e0 + pos);
      const float4 b = *(const float4*)(e1 + pos);
      float* po = dst + (size_t)row * OUT_N + bx * 128 + col;
      unsafeAtomicAdd(po + 0, a.x + b.x);
      unsafeAtomicAdd(po + 1, a.y + b.y);
      unsafeAtomicAdd(po + 2, a.z + b.z);
      unsafeAtomicAdd(po + 3, a.w + b.w);
    }
  } else {
    float* pout = dst + ((size_t)bx * 2 + by) * 8192;
#pragma unroll
    for (int i = 0; i < 4; ++i) {
      const int pos = tid * 16 + i * 4;
      const float4 a = *(const float4*)(e0 + pos);
      const float4 b = *(const float4*)(e1 + pos);
      float4 r; r.x = a.x + b.x; r.y = a.y + b.y; r.z = a.z + b.z; r.w = a.w + b.w;
      *(float4*)(pout + pos) = r;
    }
  }
}

// ---------------------------------------------------------------------------
extern "C" void kernel_launch(void* const* d_in, const int* in_sizes, int n_in,
                              void* d_out, int out_size, void* d_ws, size_t ws_size,
                              hipStream_t stream) {
  (void)in_sizes; (void)n_in; (void)out_size;
  const float* x    = (const float*)d_in[0];
  const u32*   qw   = (const u32*)d_in[1];
  const u32*   qz   = (const u32*)d_in[2];
  const float* sc   = (const float*)d_in[3];
  const float* bias = (const float*)d_in[4];
  // d_in[5] = g_idx: sequential k/128 for this problem; folded into indexing.
  float* out = (float*)d_out;

  const size_t XS_BYTES   = (size_t)64 * IN_K * 2;             // 512 KB
  const size_t PART_BYTES = (size_t)112 * 2 * 8192 * 4;        // 7.34 MB
  u16* xs = (u16*)d_ws;

  prep_kernel<<<128, 256, 0, stream>>>(x, xs);

  if (ws_size >= XS_BYTES + PART_BYTES) {
    float* part = (float*)((char*)d_ws + XS_BYTES);
    qgemm_kernel<false><<<dim3(112, 2), 512, 0, stream>>>(qw, qz, sc, xs, part);
    reduce_kernel<<<dim3(112, 8), 256, 0, stream>>>(part, bias, out);
  } else {
    bias_init_kernel<<<896, 256, 0, stream>>>(bias, out);
    qgemm_kernel<true><<<dim3(112, 2), 512, 0, stream>>>(qw, qz, sc, xs, out);
  }
}

// Round 21
// 26.877 us; speedup vs baseline: 1.3623x; 1.0875x over previous
//
#include <hip/hip_runtime.h>
#include <hip/hip_bf16.h>

using u32 = unsigned int;
using u16 = unsigned short;

typedef __attribute__((ext_vector_type(8))) _Float16 half8;
typedef __attribute__((ext_vector_type(2))) _Float16 half2v;
typedef __attribute__((ext_vector_type(16))) float f32x16;
typedef __attribute__((ext_vector_type(4))) u32 u32x4;

#define IN_K   4096
#define OUT_N  14336
#define NST    16                // 16 stages x 64k = 1024k per k-quarter

// ---------------------------------------------------------------------------
// prep: x f32[64][4096] -> xs f16 in MFMA-fragment order.
// xs layout: [512 chunks][64 rows][8 f16]; chunk c covers k = 8c + perm[j],
// perm = {0,4,1,5,2,6,3,7} (matches pair-dequant element order).
__global__ __launch_bounds__(256) void prep_kernel(const float* __restrict__ x,
                                                   u16* __restrict__ xs) {
  const int t = blockIdx.x * 256 + threadIdx.x;   // 32768 threads
  const int c = t >> 6;        // chunk 0..511
  const int r = t & 63;        // row
  const float* px = x + r * IN_K + c * 8;
  const float4 a = *(const float4*)px;
  const float4 b = *(const float4*)(px + 4);
  const float af[4] = {a.x, a.y, a.z, a.w};
  const float bf[4] = {b.x, b.y, b.z, b.w};
  union { u32x4 v; u32 u[4]; } o;
#pragma unroll
  for (int i = 0; i < 4; ++i) {
    const _Float16 hl = (_Float16)af[i];   // k = 8c + i
    const _Float16 hh = (_Float16)bf[i];   // k = 8c + i + 4
    u16 lo, hi;
    __builtin_memcpy(&lo, &hl, 2);
    __builtin_memcpy(&hi, &hh, 2);
    o.u[i] = (u32)lo | ((u32)hi << 16);
  }
  *(u32x4*)(xs + (size_t)t * 8) = o.v;
}

// dequant one qweight word (8 weights, fragment order) -> f16x8 B-fragment
static __device__ __forceinline__ half8 dequant8(u32 q, half2v hz, half2v s2) {
  const u32 p0 = (q & 0x000F000Fu) | 0x64006400u;          // (n0,n4)+1024
  const u32 p1 = ((q >> 4) & 0x000F000Fu) | 0x64006400u;   // (n1,n5)+1024
  const u32 p2 = ((q >> 8) & 0x000F000Fu) | 0x64006400u;   // (n2,n6)+1024
  const u32 p3 = ((q >> 12) & 0x000F000Fu) | 0x64006400u;  // (n3,n7)+1024
  half2v t0, t1, t2, t3;
  __builtin_memcpy(&t0, &p0, 4);
  __builtin_memcpy(&t1, &p1, 4);
  __builtin_memcpy(&t2, &p2, 4);
  __builtin_memcpy(&t3, &p3, 4);
  union { half8 v; half2v h[4]; } bb;
  bb.h[0] = (t0 - hz) * s2;    // exact int sub, then scale (v_pk_*_f16)
  bb.h[1] = (t1 - hz) * s2;
  bb.h[2] = (t2 - hz) * s2;
  bb.h[3] = (t3 - hz) * s2;
  return bb.v;
}

// ---------------------------------------------------------------------------
// Fused qgemm (R13 geometry; staging path is the ONE variable): both A and Q
// staged via plain global dwordx4 -> VGPR -> ds_write_b128 (T14 async split:
// loads issued one stage ahead, writes after the WAR barrier). NO manual
// vmcnt anywhere -- all VMEM waits are compiler-inserted register deps, so
// the R20 ordering bug class is structurally impossible.
// Grid 224 x 512 thr (8 waves = 4 k-quarters x 2 col-halves); per-quarter
// ring-2 stages {A 8 KB + Q 2 KB}; in-block split-K LDS epilogue; 2 launches.
__global__ __launch_bounds__(512, 4) void qgemm_kernel(
    const u32* __restrict__ qw, const u32* __restrict__ qz,
    const float* __restrict__ scal, const u16* __restrict__ xs,
    const float* __restrict__ bias, float* __restrict__ out) {
  __shared__ alignas(16) char smem[81920];   // 4 x {A 2x8KB + Q 2x2KB}
  const int tid = threadIdx.x;               // 0..511
  const int lane = tid & 63;
  const int g = lane >> 5;                   // k-half within 16k step
  const int nn = lane & 31;
  const int wv = tid >> 6;                   // 0..7
  const int ch = wv & 1;                     // col-half (32 cols)
  const int kq = wv >> 1;                    // k-quarter (1024 k)
  const int tq = tid & 127;                  // thread id within quarter pair
  const int bx = blockIdx.x;
  const int colabs = bx * 64 + ch * 32 + nn;
  const int zsh = (nn & 7) * 4;
  char* const base = smem + kq * 20480;      // A 2x8KB @0, Q 2x2KB @16384

  f32x16 acc0, acc1;
#pragma unroll
  for (int i = 0; i < 16; ++i) { acc0[i] = 0.f; acc1[i] = 0.f; }

  // scales & zero-words for this quarter's 8 groups -> registers
  float sv[8]; u32 zv[8];
#pragma unroll
  for (int t = 0; t < 8; ++t) {
    sv[t] = scal[(size_t)(kq * 8 + t) * OUT_N + colabs];
    zv[t] = qz[(size_t)(kq * 8 + t) * (OUT_N / 8) + (colabs >> 3)];
  }

  // ---- reg staging (quarter-shared): A 4 x dwordx4 + Q 1 x dwordx4 ----
  auto loadStage = [&](int st, u32x4* ra, u32x4& rq) {
    const char* asrc = (const char*)(xs + (size_t)(kq * 128 + st * 8) * 512);
#pragma unroll
    for (int r = 0; r < 4; ++r)
      ra[r] = *(const u32x4*)(asrc + (r * 128 + tq) * 16);
    const int j = tq >> 4, cg = tq & 15;     // Q: 8 rows x 256 B
    rq = *(const u32x4*)(qw + (size_t)(kq * 128 + st * 8 + j) * OUT_N
                            + bx * 64 + cg * 4);
  };
  auto writeStage = [&](int st, const u32x4* ra, u32x4 rq) {
    char* ab = base + (st & 1) * 8192;
#pragma unroll
    for (int r = 0; r < 4; ++r)
      *(u32x4*)(ab + (r * 128 + tq) * 16) = ra[r];     // ds_write_b128
    char* qb = base + 16384 + (st & 1) * 2048;
    *(u32x4*)(qb + tq * 16) = rq;
  };

  u32x4 ra[2][4]; u32x4 rq[2];
  loadStage(0, ra[0], rq[0]);
  writeStage(0, ra[0], rq[0]);               // compiler waits vmcnt for regs
  loadStage(1, ra[1], rq[1]);                // stage-1 loads fly during barrier
  asm volatile("s_waitcnt lgkmcnt(0)" ::: "memory");
  __builtin_amdgcn_s_barrier();              // stage 0 visible
  asm volatile("" ::: "memory");

#pragma unroll
  for (int st = 0; st < NST; ++st) {
    // ---- compute stage st from slot st&1 ----
    const int gi = st >> 1;                  // group = 128 k = 2 stages
    const u32 zq = (zv[gi] >> zsh) & 0xFu;
    const u32 hzu = 0x64016401u + zq * 0x00010001u;      // f16x2 of (1025+z)
    half2v hz; __builtin_memcpy(&hz, &hzu, 4);
    const _Float16 hs = (_Float16)sv[gi];
    const half2v s2 = {hs, hs};

    const u16* ab = (const u16*)(base + (st & 1) * 8192);
    const u32* qb = (const u32*)(base + 16384 + (st & 1) * 2048);
    __builtin_amdgcn_s_setprio(1);
#pragma unroll
    for (int s = 0; s < 4; ++s) {
      const int cl = s * 2 + g;              // chunk within stage (0..7)
      const half8 a0 = *(const half8*)(ab + (cl * 64 + nn) * 8);
      const half8 a1 = *(const half8*)(ab + (cl * 64 + nn + 32) * 8);
      const u32 q = qb[cl * 64 + ch * 32 + nn];
      const half8 bb = dequant8(q, hz, s2);
      acc0 = __builtin_amdgcn_mfma_f32_32x32x16_f16(a0, bb, acc0, 0, 0, 0);
      acc1 = __builtin_amdgcn_mfma_f32_32x32x16_f16(a1, bb, acc1, 0, 0, 0);
    }
    __builtin_amdgcn_s_setprio(0);

    if (st + 1 < NST) {
      __builtin_amdgcn_s_barrier();          // WAR: slot (st+1)&1 free (all waves)
      asm volatile("" ::: "memory");
      writeStage(st + 1, ra[(st + 1) & 1], rq[(st + 1) & 1]);
      if (st + 2 < NST)
        loadStage(st + 2, ra[st & 1], rq[st & 1]);   // issue early, used next iter
      asm volatile("s_waitcnt lgkmcnt(0)" ::: "memory");  // own writes committed
      __builtin_amdgcn_s_barrier();          // stage st+1 visible
      asm volatile("" ::: "memory");
    }
  }

  // ---- in-block split-K reduction via LDS (reuses ring space) ----
  __syncthreads();                           // all compute reads done
  float* ep = (float*)smem + kq * 4096;      // [64 rows][64 cols] f32 (16 KB)
#pragma unroll
  for (int r = 0; r < 16; ++r) {
    const int row0 = (r & 3) + 8 * (r >> 2) + 4 * g;
    ep[row0 * 64 + ch * 32 + nn] = acc0[r];
    ep[(row0 + 32) * 64 + ch * 32 + nn] = acc1[r];
  }
  __syncthreads();
  // 512 threads x 8 f32: sum 4 regions + bias -> out (order: bias, q0..q3)
  const int pos = tid * 8;
  const int row = pos >> 6;
  const int colb = pos & 63;
  const float* eb = (const float*)smem;
  float4 v0 = *(const float4*)(bias + bx * 64 + colb);
  float4 v1 = *(const float4*)(bias + bx * 64 + colb + 4);
#pragma unroll
  for (int q = 0; q < 4; ++q) {
    const float4 a = *(const float4*)(eb + q * 4096 + pos);
    const float4 b = *(const float4*)(eb + q * 4096 + pos + 4);
    v0.x += a.x; v0.y += a.y; v0.z += a.z; v0.w += a.w;
    v1.x += b.x; v1.y += b.y; v1.z += b.z; v1.w += b.w;
  }
  float* po = out + (size_t)row * OUT_N + bx * 64 + colb;
  *(float4*)po = v0;
  *(float4*)(po + 4) = v1;
}

// ---------------------------------------------------------------------------
extern "C" void kernel_launch(void* const* d_in, const int* in_sizes, int n_in,
                              void* d_out, int out_size, void* d_ws, size_t ws_size,
                              hipStream_t stream) {
  (void)in_sizes; (void)n_in; (void)out_size; (void)ws_size;
  const float* x    = (const float*)d_in[0];
  const u32*   qw   = (const u32*)d_in[1];
  const u32*   qz   = (const u32*)d_in[2];
  const float* sc   = (const float*)d_in[3];
  const float* bias = (const float*)d_in[4];
  // d_in[5] = g_idx: sequential k/128 for this problem; folded into indexing.
  float* out = (float*)d_out;
  u16* xs = (u16*)d_ws;                      // 512 KB scratch

  prep_kernel<<<128, 256, 0, stream>>>(x, xs);
  qgemm_kernel<<<224, 512, 0, stream>>>(qw, qz, sc, xs, bias, out);
}